// Round 1
// baseline (376.370 us; speedup 1.0000x reference)
//
#include <hip/hip_runtime.h>
#include <math.h>

#define BATCH 2
#define DCH 64
#define PIX (512 * 512)
#define NSEG 641          // N_CLASSES*MAX_INDEX + 1
#define NCLS 5
#define IGNORE_LB 255
#define GCH 8             // channels per block in k_sums
#define TI 16             // pair-tile edge

// ---- workspace layout (bytes) ----
// zero region (memset each call):
#define OFF_M     0                                   // int m[BATCH]
#define OFF_PAIR  64                                  // float pairsum[BATCH][25]
#define OFF_CNT   320                                 // uint counts[BATCH][NSEG]
#define OFF_SUM   5504                                // float sums[BATCH][NSEG][DCH]
#define ZERO_BYTES (OFF_SUM + BATCH * NSEG * DCH * 4) // = 333,696
// non-zeroed (fully rewritten each call):
#define OFF_MEAN  ZERO_BYTES                          // float means[BATCH][NSEG][DCH]
#define OFF_KEYS  (OFF_MEAN + BATCH * NSEG * DCH * 4) // ushort keys[BATCH][PIX]

__global__ void k_max(const int* __restrict__ idx, int* __restrict__ mout) {
    const int b = blockIdx.y;
    const int* p = idx + (size_t)b * PIX;
    int v = 0;
    for (int i = blockIdx.x * blockDim.x + threadIdx.x; i < PIX;
         i += gridDim.x * blockDim.x)
        v = max(v, p[i]);
    #pragma unroll
    for (int o = 32; o; o >>= 1) v = max(v, __shfl_down(v, o, 64));
    if ((threadIdx.x & 63) == 0) atomicMax(&mout[b], v);
}

__global__ void k_keys(const int* __restrict__ lab, const int* __restrict__ idx,
                       const int* __restrict__ mbuf,
                       unsigned short* __restrict__ keys,
                       unsigned int* __restrict__ counts) {
    __shared__ unsigned int hist[NSEG];
    const int b = blockIdx.y;
    for (int i = threadIdx.x; i < NSEG; i += blockDim.x) hist[i] = 0u;
    __syncthreads();
    const int m = mbuf[b];
    const int* lb = lab + (size_t)b * PIX;
    const int* ib = idx + (size_t)b * PIX;
    unsigned short* kb = keys + (size_t)b * PIX;
    for (int i = blockIdx.x * blockDim.x + threadIdx.x; i < PIX;
         i += gridDim.x * blockDim.x) {
        int l = lb[i], x = ib[i];
        if (l == IGNORE_LB) { l = 0; x = 0; }
        int k = m * l + x;
        kb[i] = (unsigned short)k;
        atomicAdd(&hist[k], 1u);
    }
    __syncthreads();
    for (int i = threadIdx.x; i < NSEG; i += blockDim.x)
        if (hist[i]) atomicAdd(&counts[b * NSEG + i], hist[i]);
}

__global__ void k_sums(const float* __restrict__ feat,
                       const unsigned short* __restrict__ keys,
                       float* __restrict__ sums) {
    __shared__ float acc[GCH][NSEG];   // 20.5 KB
    const int b = blockIdx.z, g0 = blockIdx.y * GCH;
    for (int i = threadIdx.x; i < GCH * NSEG; i += blockDim.x)
        ((float*)acc)[i] = 0.f;
    __syncthreads();
    const int chunk = PIX / gridDim.x;
    const int base = blockIdx.x * chunk;
    const unsigned short* kb = keys + (size_t)b * PIX + base;
    const float* fb = feat + ((size_t)b * DCH + g0) * PIX + base;
    for (int i = threadIdx.x; i < chunk; i += blockDim.x) {
        const int k = kb[i];
        #pragma unroll
        for (int g = 0; g < GCH; ++g)
            atomicAdd(&acc[g][k], fb[(size_t)g * PIX + i]);
    }
    __syncthreads();
    for (int i = threadIdx.x; i < GCH * NSEG; i += blockDim.x) {
        const int s = i >> 3, g = i & (GCH - 1);
        const float v = acc[g][s];
        if (v != 0.f)
            atomicAdd(&sums[((size_t)b * NSEG + s) * DCH + g0 + g], v);
    }
}

__global__ void k_means(const float* __restrict__ sums,
                        const unsigned int* __restrict__ counts,
                        float* __restrict__ means) {
    const int s = blockIdx.x, b = blockIdx.y, d = threadIdx.x;
    const float c = (float)counts[b * NSEG + s];
    const size_t o = ((size_t)b * NSEG + s) * DCH + d;
    means[o] = sums[o] / fmaxf(c, 1.f);
}

__global__ void k_pairs(const float* __restrict__ means,
                        const unsigned int* __restrict__ counts,
                        const int* __restrict__ mbuf,
                        float* __restrict__ pairsum) {
    __shared__ float rI[TI][DCH + 1], rJ[TI][DCH + 1];  // +1 pad: kill 16-way bank conflict
    __shared__ int cI[TI], cJ[TI];
    __shared__ float ps[NCLS * NCLS];
    const int b = blockIdx.z;
    const int i0 = blockIdx.x * TI, j0 = blockIdx.y * TI;
    const int m = mbuf[b];
    if (threadIdx.x < NCLS * NCLS) ps[threadIdx.x] = 0.f;
    for (int t = threadIdx.x; t < TI * DCH; t += blockDim.x) {
        const int r = t >> 6, d = t & 63;
        const int si = i0 + r, sj = j0 + r;
        rI[r][d] = (si < NSEG) ? means[((size_t)b * NSEG + si) * DCH + d] : 0.f;
        rJ[r][d] = (sj < NSEG) ? means[((size_t)b * NSEG + sj) * DCH + d] : 0.f;
    }
    if (threadIdx.x < TI) {
        int si = i0 + threadIdx.x;
        bool ok = (si > 0 && si < NSEG && counts[b * NSEG + si] >= 2u);
        cI[threadIdx.x] = ok ? (si + m - 1) / m - 1 : -1;
        int sj = j0 + threadIdx.x;
        ok = (sj > 0 && sj < NSEG && counts[b * NSEG + sj] >= 2u);
        cJ[threadIdx.x] = ok ? (sj + m - 1) / m - 1 : -1;
    }
    __syncthreads();
    const int ti = threadIdx.x >> 4, tj = threadIdx.x & 15;
    const int ci = cI[ti], cj = cJ[tj];
    if (ci >= 0 && ci < NCLS && cj >= 0 && cj < NCLS) {
        float s = 0.f;
        #pragma unroll
        for (int d = 0; d < DCH; ++d) s += fabsf(rI[ti][d] - rJ[tj][d]);
        atomicAdd(&ps[ci * NCLS + cj], s * (1.f / DCH));
    }
    __syncthreads();
    if (threadIdx.x < NCLS * NCLS && ps[threadIdx.x] != 0.f)
        atomicAdd(&pairsum[b * NCLS * NCLS + threadIdx.x], ps[threadIdx.x]);
}

__global__ void k_final(const unsigned int* __restrict__ counts,
                        const float* __restrict__ pairsum,
                        const int* __restrict__ mbuf,
                        float* __restrict__ out) {
    float tot_s = 0.f, tot_c = 0.f;
    for (int b = 0; b < BATCH; ++b) {
        const int m = mbuf[b];
        int nc[NCLS] = {0, 0, 0, 0, 0};
        for (int s = 1; s < NSEG; ++s)
            if (counts[b * NSEG + s] >= 2u) {
                const int c = (s + m - 1) / m - 1;
                if (c >= 0 && c < NCLS) nc[c]++;
            }
        for (int c1 = 0; c1 < NCLS; ++c1)
            for (int c2 = c1 + 1; c2 < NCLS; ++c2) {
                const float np = (float)nc[c1] * (float)nc[c2];
                if (np > 0.f) {
                    const float r = pairsum[b * NCLS * NCLS + c1 * NCLS + c2] / np;
                    const float h = (r < 1.f) ? 0.5f * r * r : r - 0.5f;
                    tot_s += h;
                    tot_c += 1.f;
                }
            }
    }
    float mh = tot_s / fmaxf(tot_c, 1.f);
    mh = fmaxf(mh, 1e-12f);
    out[0] = (tot_c > 0.f) ? -logf(mh / (float)BATCH) : 0.f;
}

extern "C" void kernel_launch(void* const* d_in, const int* in_sizes, int n_in,
                              void* d_out, int out_size, void* d_ws, size_t ws_size,
                              hipStream_t stream) {
    const float* feat = (const float*)d_in[0];
    const int* lab = (const int*)d_in[1];
    const int* idx = (const int*)d_in[2];
    float* out = (float*)d_out;
    char* ws = (char*)d_ws;

    int* mbuf            = (int*)(ws + OFF_M);
    float* pairsum       = (float*)(ws + OFF_PAIR);
    unsigned int* counts = (unsigned int*)(ws + OFF_CNT);
    float* sums          = (float*)(ws + OFF_SUM);
    float* means         = (float*)(ws + OFF_MEAN);
    unsigned short* keys = (unsigned short*)(ws + OFF_KEYS);

    hipMemsetAsync(ws, 0, ZERO_BYTES, stream);
    k_max<<<dim3(32, BATCH), 256, 0, stream>>>(idx, mbuf);
    k_keys<<<dim3(64, BATCH), 256, 0, stream>>>(lab, idx, mbuf, keys, counts);
    k_sums<<<dim3(64, DCH / GCH, BATCH), 256, 0, stream>>>(feat, keys, sums);
    k_means<<<dim3(NSEG, BATCH), DCH, 0, stream>>>(sums, counts, means);
    k_pairs<<<dim3((NSEG + TI - 1) / TI, (NSEG + TI - 1) / TI, BATCH), 256, 0, stream>>>(
        means, counts, mbuf, pairsum);
    k_final<<<1, 1, 0, stream>>>(counts, pairsum, mbuf, out);
}

// Round 2
// 234.212 us; speedup vs baseline: 1.6070x; 1.6070x over previous
//
#include <hip/hip_runtime.h>
#include <math.h>

#define BATCH 2
#define DCH 64
#define PIX (512 * 512)
#define NSEG 641          // N_CLASSES*MAX_INDEX + 1
#define NCLS 5
#define IGNORE_LB 255
#define GCH 8             // channels per block in k_sums
#define TI 16             // pair-tile edge

// ---- workspace layout (bytes) ----
// zero region (memset each call):
#define OFF_M     0                                   // int m[BATCH]
#define OFF_PAIR  64                                  // float pairsum[BATCH][25]
#define OFF_CNT   320                                 // uint counts[BATCH][NSEG]
#define OFF_SUM   5504                                // float sums[BATCH][NSEG][DCH]
#define ZERO_BYTES (OFF_SUM + BATCH * NSEG * DCH * 4) // = 333,696
// non-zeroed (fully rewritten each call):
#define OFF_KEYS  ZERO_BYTES                          // ushort keys[BATCH][PIX]

__global__ void k_max(const int* __restrict__ idx, int* __restrict__ mout) {
    const int b = blockIdx.y;
    const int4* p = (const int4*)(idx + (size_t)b * PIX);
    int v = 0;
    for (int i = blockIdx.x * blockDim.x + threadIdx.x; i < PIX / 4;
         i += gridDim.x * blockDim.x) {
        const int4 q = p[i];
        v = max(v, max(max(q.x, q.y), max(q.z, q.w)));
    }
    #pragma unroll
    for (int o = 32; o; o >>= 1) v = max(v, __shfl_down(v, o, 64));
    if ((threadIdx.x & 63) == 0) atomicMax(&mout[b], v);
}

__global__ void k_keys(const int* __restrict__ lab, const int* __restrict__ idx,
                       const int* __restrict__ mbuf,
                       unsigned short* __restrict__ keys,
                       unsigned int* __restrict__ counts) {
    __shared__ unsigned int hist[NSEG];
    const int b = blockIdx.y;
    for (int i = threadIdx.x; i < NSEG; i += blockDim.x) hist[i] = 0u;
    __syncthreads();
    const int m = mbuf[b];
    const int4* lb = (const int4*)(lab + (size_t)b * PIX);
    const int4* ib = (const int4*)(idx + (size_t)b * PIX);
    unsigned short* kb = keys + (size_t)b * PIX;
    for (int i = blockIdx.x * blockDim.x + threadIdx.x; i < PIX / 4;
         i += gridDim.x * blockDim.x) {
        const int4 l4 = lb[i];
        const int4 x4 = ib[i];
        int k[4];
        k[0] = (l4.x == IGNORE_LB) ? 0 : m * l4.x + x4.x;
        k[1] = (l4.y == IGNORE_LB) ? 0 : m * l4.y + x4.y;
        k[2] = (l4.z == IGNORE_LB) ? 0 : m * l4.z + x4.z;
        k[3] = (l4.w == IGNORE_LB) ? 0 : m * l4.w + x4.w;
        ushort4 o;
        o.x = (unsigned short)k[0]; o.y = (unsigned short)k[1];
        o.z = (unsigned short)k[2]; o.w = (unsigned short)k[3];
        *(ushort4*)(kb + 4 * i) = o;
        #pragma unroll
        for (int j = 0; j < 4; ++j) atomicAdd(&hist[k[j]], 1u);
    }
    __syncthreads();
    for (int i = threadIdx.x; i < NSEG; i += blockDim.x)
        if (hist[i]) atomicAdd(&counts[b * NSEG + i], hist[i]);
}

__global__ __launch_bounds__(256) void k_sums(const float* __restrict__ feat,
                                              const unsigned short* __restrict__ keys,
                                              float* __restrict__ sums) {
    __shared__ float acc[GCH][NSEG];   // 20.5 KB
    const int b = blockIdx.z, g0 = blockIdx.y * GCH;
    for (int i = threadIdx.x; i < GCH * NSEG; i += blockDim.x)
        ((float*)acc)[i] = 0.f;
    __syncthreads();
    const int chunk = PIX / gridDim.x;             // 4096
    const int base = blockIdx.x * chunk;
    const unsigned short* kb = keys + (size_t)b * PIX + base;
    const float* fb = feat + ((size_t)b * DCH + g0) * PIX + base;
    for (int i = threadIdx.x * 4; i < chunk; i += blockDim.x * 4) {
        const ushort4 k4 = *(const ushort4*)(kb + i);
        float4 f[GCH];
        #pragma unroll
        for (int g = 0; g < GCH; ++g)
            f[g] = *(const float4*)(fb + (size_t)g * PIX + i);
        #pragma unroll
        for (int g = 0; g < GCH; ++g) {
            atomicAdd(&acc[g][k4.x], f[g].x);
            atomicAdd(&acc[g][k4.y], f[g].y);
            atomicAdd(&acc[g][k4.z], f[g].z);
            atomicAdd(&acc[g][k4.w], f[g].w);
        }
    }
    __syncthreads();
    for (int i = threadIdx.x; i < GCH * NSEG; i += blockDim.x) {
        const int s = i >> 3, g = i & (GCH - 1);
        const float v = acc[g][s];
        if (v != 0.f)
            atomicAdd(&sums[((size_t)b * NSEG + s) * DCH + g0 + g], v);
    }
}

// pairwise tile kernel: computes means on the fly from sums/counts
__global__ void k_pairs(const float* __restrict__ sums,
                        const unsigned int* __restrict__ counts,
                        const int* __restrict__ mbuf,
                        float* __restrict__ pairsum) {
    __shared__ float rI[TI][DCH + 1], rJ[TI][DCH + 1];  // +1 pad: kill bank conflict
    __shared__ int cI[TI], cJ[TI];
    __shared__ float ps[NCLS * NCLS];
    const int b = blockIdx.z;
    const int i0 = blockIdx.x * TI, j0 = blockIdx.y * TI;
    const int m = mbuf[b];
    if (threadIdx.x < NCLS * NCLS) ps[threadIdx.x] = 0.f;
    for (int t = threadIdx.x; t < TI * DCH; t += blockDim.x) {
        const int r = t >> 6, d = t & 63;
        const int si = i0 + r, sj = j0 + r;
        float vi = 0.f, vj = 0.f;
        if (si < NSEG) {
            const float c = fmaxf((float)counts[b * NSEG + si], 1.f);
            vi = sums[((size_t)b * NSEG + si) * DCH + d] / c;
        }
        if (sj < NSEG) {
            const float c = fmaxf((float)counts[b * NSEG + sj], 1.f);
            vj = sums[((size_t)b * NSEG + sj) * DCH + d] / c;
        }
        rI[r][d] = vi;
        rJ[r][d] = vj;
    }
    if (threadIdx.x < TI) {
        int si = i0 + threadIdx.x;
        bool ok = (si > 0 && si < NSEG && counts[b * NSEG + si] >= 2u);
        cI[threadIdx.x] = ok ? (si + m - 1) / m - 1 : -1;
        int sj = j0 + threadIdx.x;
        ok = (sj > 0 && sj < NSEG && counts[b * NSEG + sj] >= 2u);
        cJ[threadIdx.x] = ok ? (sj + m - 1) / m - 1 : -1;
    }
    __syncthreads();
    const int ti = threadIdx.x >> 4, tj = threadIdx.x & 15;
    const int ci = cI[ti], cj = cJ[tj];
    if (ci >= 0 && ci < NCLS && cj >= 0 && cj < NCLS) {
        float s = 0.f;
        #pragma unroll
        for (int d = 0; d < DCH; ++d) s += fabsf(rI[ti][d] - rJ[tj][d]);
        atomicAdd(&ps[ci * NCLS + cj], s * (1.f / DCH));
    }
    __syncthreads();
    if (threadIdx.x < NCLS * NCLS && ps[threadIdx.x] != 0.f)
        atomicAdd(&pairsum[b * NCLS * NCLS + threadIdx.x], ps[threadIdx.x]);
}

__global__ void k_final(const unsigned int* __restrict__ counts,
                        const float* __restrict__ pairsum,
                        const int* __restrict__ mbuf,
                        float* __restrict__ out) {
    __shared__ int nc[BATCH][NCLS];
    __shared__ float psl[BATCH * NCLS * NCLS];
    __shared__ int ml[BATCH];
    const int tid = threadIdx.x;
    if (tid < BATCH * NCLS) nc[tid / NCLS][tid % NCLS] = 0;
    if (tid < BATCH * NCLS * NCLS) psl[tid] = pairsum[tid];
    if (tid < BATCH) ml[tid] = mbuf[tid];
    __syncthreads();
    for (int t = tid; t < BATCH * NSEG; t += blockDim.x) {
        const int b = t / NSEG, s = t % NSEG;
        if (s > 0 && counts[t] >= 2u) {
            const int m = ml[b];
            const int c = (s + m - 1) / m - 1;
            if (c >= 0 && c < NCLS) atomicAdd(&nc[b][c], 1);
        }
    }
    __syncthreads();
    if (tid == 0) {
        float tot_s = 0.f, tot_c = 0.f;
        for (int b = 0; b < BATCH; ++b)
            for (int c1 = 0; c1 < NCLS; ++c1)
                for (int c2 = c1 + 1; c2 < NCLS; ++c2) {
                    const float np = (float)nc[b][c1] * (float)nc[b][c2];
                    if (np > 0.f) {
                        const float r = psl[b * NCLS * NCLS + c1 * NCLS + c2] / np;
                        tot_s += (r < 1.f) ? 0.5f * r * r : r - 0.5f;
                        tot_c += 1.f;
                    }
                }
        float mh = tot_s / fmaxf(tot_c, 1.f);
        mh = fmaxf(mh, 1e-12f);
        out[0] = (tot_c > 0.f) ? -logf(mh / (float)BATCH) : 0.f;
    }
}

extern "C" void kernel_launch(void* const* d_in, const int* in_sizes, int n_in,
                              void* d_out, int out_size, void* d_ws, size_t ws_size,
                              hipStream_t stream) {
    const float* feat = (const float*)d_in[0];
    const int* lab = (const int*)d_in[1];
    const int* idx = (const int*)d_in[2];
    float* out = (float*)d_out;
    char* ws = (char*)d_ws;

    int* mbuf            = (int*)(ws + OFF_M);
    float* pairsum       = (float*)(ws + OFF_PAIR);
    unsigned int* counts = (unsigned int*)(ws + OFF_CNT);
    float* sums          = (float*)(ws + OFF_SUM);
    unsigned short* keys = (unsigned short*)(ws + OFF_KEYS);

    hipMemsetAsync(ws, 0, ZERO_BYTES, stream);
    k_max<<<dim3(32, BATCH), 256, 0, stream>>>(idx, mbuf);
    k_keys<<<dim3(64, BATCH), 256, 0, stream>>>(lab, idx, mbuf, keys, counts);
    k_sums<<<dim3(64, DCH / GCH, BATCH), 256, 0, stream>>>(feat, keys, sums);
    k_pairs<<<dim3((NSEG + TI - 1) / TI, (NSEG + TI - 1) / TI, BATCH), 256, 0, stream>>>(
        sums, counts, mbuf, pairsum);
    k_final<<<1, 256, 0, stream>>>(counts, pairsum, mbuf, out);
}

// Round 3
// 233.329 us; speedup vs baseline: 1.6130x; 1.0038x over previous
//
#include <hip/hip_runtime.h>
#include <math.h>

#define BATCH 2
#define DCH 64
#define PIX (512 * 512)
#define NSEG 641          // N_CLASSES*MAX_INDEX + 1
#define NCLS 5
#define IGNORE_LB 255
#define GCH 8             // channels per block in k_sums
#define NGRP (DCH / GCH)  // 8 channel groups
#define XCH 32            // pixel chunks in k_sums
#define TI 16             // pair-tile edge

// ---- workspace layout (bytes) ----
// zero region (memset each call):
#define OFF_M     0                                   // int m[BATCH]
#define OFF_PAIR  64                                  // float pairsum[BATCH][25]
#define OFF_CNT   320                                 // uint counts[BATCH][NSEG]
#define ZERO_BYTES 5504
// non-zeroed (fully rewritten each call):
#define OFF_SUM   ZERO_BYTES                          // float sums[BATCH][NSEG][DCH]
#define OFF_PART  (OFF_SUM + BATCH * NSEG * DCH * 4)  // float partials[BATCH][NGRP][XCH][GCH*NSEG]
#define OFF_KEYS  (OFF_PART + BATCH * NGRP * XCH * GCH * NSEG * 4) // ushort keys[BATCH][PIX]

__global__ void k_max(const int* __restrict__ idx, int* __restrict__ mout) {
    const int b = blockIdx.y;
    const int4* p = (const int4*)(idx + (size_t)b * PIX);
    int v = 0;
    for (int i = blockIdx.x * blockDim.x + threadIdx.x; i < PIX / 4;
         i += gridDim.x * blockDim.x) {
        const int4 q = p[i];
        v = max(v, max(max(q.x, q.y), max(q.z, q.w)));
    }
    #pragma unroll
    for (int o = 32; o; o >>= 1) v = max(v, __shfl_down(v, o, 64));
    if ((threadIdx.x & 63) == 0) atomicMax(&mout[b], v);
}

__global__ void k_keys(const int* __restrict__ lab, const int* __restrict__ idx,
                       const int* __restrict__ mbuf,
                       unsigned short* __restrict__ keys,
                       unsigned int* __restrict__ counts) {
    __shared__ unsigned int hist[NSEG];
    const int b = blockIdx.y;
    for (int i = threadIdx.x; i < NSEG; i += blockDim.x) hist[i] = 0u;
    __syncthreads();
    const int m = mbuf[b];
    const int4* lb = (const int4*)(lab + (size_t)b * PIX);
    const int4* ib = (const int4*)(idx + (size_t)b * PIX);
    unsigned short* kb = keys + (size_t)b * PIX;
    for (int i = blockIdx.x * blockDim.x + threadIdx.x; i < PIX / 4;
         i += gridDim.x * blockDim.x) {
        const int4 l4 = lb[i];
        const int4 x4 = ib[i];
        int k[4];
        k[0] = (l4.x == IGNORE_LB) ? 0 : m * l4.x + x4.x;
        k[1] = (l4.y == IGNORE_LB) ? 0 : m * l4.y + x4.y;
        k[2] = (l4.z == IGNORE_LB) ? 0 : m * l4.z + x4.z;
        k[3] = (l4.w == IGNORE_LB) ? 0 : m * l4.w + x4.w;
        ushort4 o;
        o.x = (unsigned short)k[0]; o.y = (unsigned short)k[1];
        o.z = (unsigned short)k[2]; o.w = (unsigned short)k[3];
        *(ushort4*)(kb + 4 * i) = o;
        #pragma unroll
        for (int j = 0; j < 4; ++j) atomicAdd(&hist[k[j]], 1u);
    }
    __syncthreads();
    for (int i = threadIdx.x; i < NSEG; i += blockDim.x)
        if (hist[i]) atomicAdd(&counts[b * NSEG + i], hist[i]);
}

// Each block: 8 channels x 8192 pixels -> LDS table -> non-atomic partial dump.
// The mid-loop __syncthreads() forces all 8 float4 loads (per wave) to issue
// BEFORE any wait -> burst memory-level parallelism the regalloc can't undo.
__global__ __launch_bounds__(256) void k_sums(const float* __restrict__ feat,
                                              const unsigned short* __restrict__ keys,
                                              float* __restrict__ partials) {
    __shared__ float acc[GCH * NSEG];   // 20.5 KB
    const int b = blockIdx.z, grp = blockIdx.y, g0 = grp * GCH;
    for (int i = threadIdx.x; i < GCH * NSEG; i += blockDim.x) acc[i] = 0.f;
    __syncthreads();
    const int chunk = PIX / XCH;                   // 8192
    const int base = blockIdx.x * chunk;
    const unsigned short* kb = keys + (size_t)b * PIX + base;
    const float* fb = feat + ((size_t)b * DCH + g0) * PIX + base;
    for (int i = threadIdx.x * 4; i < chunk; i += blockDim.x * 4) {
        const ushort4 k4 = *(const ushort4*)(kb + i);
        float4 f[GCH];
        #pragma unroll
        for (int g = 0; g < GCH; ++g)
            f[g] = *(const float4*)(fb + (size_t)g * PIX + i);
        __syncthreads();   // all loads issued wave-wide before the vmcnt wait
        #pragma unroll
        for (int g = 0; g < GCH; ++g) {
            atomicAdd(&acc[g * NSEG + k4.x], f[g].x);
            atomicAdd(&acc[g * NSEG + k4.y], f[g].y);
            atomicAdd(&acc[g * NSEG + k4.z], f[g].z);
            atomicAdd(&acc[g * NSEG + k4.w], f[g].w);
        }
    }
    __syncthreads();
    float* dst = partials +
        (size_t)(((b * NGRP + grp) * XCH + blockIdx.x)) * (GCH * NSEG);
    for (int i = threadIdx.x; i < GCH * NSEG; i += blockDim.x) dst[i] = acc[i];
}

// Reduce XCH partials -> sums[b][s][d]. Coalesced reads along s.
__global__ void k_reduce(const float* __restrict__ partials,
                         float* __restrict__ sums) {
    const int t = blockIdx.x * blockDim.x + threadIdx.x;
    if (t >= BATCH * NGRP * GCH * NSEG) return;
    const int s = t % NSEG;
    int r = t / NSEG;
    const int g = r % GCH; r /= GCH;
    const int grp = r % NGRP;
    const int b = r / NGRP;
    const float* p = partials +
        (size_t)((b * NGRP + grp) * XCH) * (GCH * NSEG) + g * NSEG + s;
    float v = 0.f;
    #pragma unroll 4
    for (int x = 0; x < XCH; ++x) v += p[(size_t)x * (GCH * NSEG)];
    sums[((size_t)b * NSEG + s) * DCH + grp * GCH + g] = v;
}

// pairwise tile kernel: computes means on the fly from sums/counts
__global__ void k_pairs(const float* __restrict__ sums,
                        const unsigned int* __restrict__ counts,
                        const int* __restrict__ mbuf,
                        float* __restrict__ pairsum) {
    __shared__ float rI[TI][DCH + 1], rJ[TI][DCH + 1];  // +1 pad: kill bank conflict
    __shared__ int cI[TI], cJ[TI];
    __shared__ float ps[NCLS * NCLS];
    const int b = blockIdx.z;
    const int i0 = blockIdx.x * TI, j0 = blockIdx.y * TI;
    const int m = mbuf[b];
    if (threadIdx.x < NCLS * NCLS) ps[threadIdx.x] = 0.f;
    for (int t = threadIdx.x; t < TI * DCH; t += blockDim.x) {
        const int r = t >> 6, d = t & 63;
        const int si = i0 + r, sj = j0 + r;
        float vi = 0.f, vj = 0.f;
        if (si < NSEG) {
            const float c = fmaxf((float)counts[b * NSEG + si], 1.f);
            vi = sums[((size_t)b * NSEG + si) * DCH + d] / c;
        }
        if (sj < NSEG) {
            const float c = fmaxf((float)counts[b * NSEG + sj], 1.f);
            vj = sums[((size_t)b * NSEG + sj) * DCH + d] / c;
        }
        rI[r][d] = vi;
        rJ[r][d] = vj;
    }
    if (threadIdx.x < TI) {
        int si = i0 + threadIdx.x;
        bool ok = (si > 0 && si < NSEG && counts[b * NSEG + si] >= 2u);
        cI[threadIdx.x] = ok ? (si + m - 1) / m - 1 : -1;
        int sj = j0 + threadIdx.x;
        ok = (sj > 0 && sj < NSEG && counts[b * NSEG + sj] >= 2u);
        cJ[threadIdx.x] = ok ? (sj + m - 1) / m - 1 : -1;
    }
    __syncthreads();
    const int ti = threadIdx.x >> 4, tj = threadIdx.x & 15;
    const int ci = cI[ti], cj = cJ[tj];
    if (ci >= 0 && ci < NCLS && cj >= 0 && cj < NCLS) {
        float s = 0.f;
        #pragma unroll
        for (int d = 0; d < DCH; ++d) s += fabsf(rI[ti][d] - rJ[tj][d]);
        atomicAdd(&ps[ci * NCLS + cj], s * (1.f / DCH));
    }
    __syncthreads();
    if (threadIdx.x < NCLS * NCLS && ps[threadIdx.x] != 0.f)
        atomicAdd(&pairsum[b * NCLS * NCLS + threadIdx.x], ps[threadIdx.x]);
}

__global__ void k_final(const unsigned int* __restrict__ counts,
                        const float* __restrict__ pairsum,
                        const int* __restrict__ mbuf,
                        float* __restrict__ out) {
    __shared__ int nc[BATCH][NCLS];
    __shared__ float psl[BATCH * NCLS * NCLS];
    __shared__ int ml[BATCH];
    const int tid = threadIdx.x;
    if (tid < BATCH * NCLS) nc[tid / NCLS][tid % NCLS] = 0;
    if (tid < BATCH * NCLS * NCLS) psl[tid] = pairsum[tid];
    if (tid < BATCH) ml[tid] = mbuf[tid];
    __syncthreads();
    for (int t = tid; t < BATCH * NSEG; t += blockDim.x) {
        const int b = t / NSEG, s = t % NSEG;
        if (s > 0 && counts[t] >= 2u) {
            const int m = ml[b];
            const int c = (s + m - 1) / m - 1;
            if (c >= 0 && c < NCLS) atomicAdd(&nc[b][c], 1);
        }
    }
    __syncthreads();
    if (tid == 0) {
        float tot_s = 0.f, tot_c = 0.f;
        for (int b = 0; b < BATCH; ++b)
            for (int c1 = 0; c1 < NCLS; ++c1)
                for (int c2 = c1 + 1; c2 < NCLS; ++c2) {
                    const float np = (float)nc[b][c1] * (float)nc[b][c2];
                    if (np > 0.f) {
                        const float r = psl[b * NCLS * NCLS + c1 * NCLS + c2] / np;
                        tot_s += (r < 1.f) ? 0.5f * r * r : r - 0.5f;
                        tot_c += 1.f;
                    }
                }
        float mh = tot_s / fmaxf(tot_c, 1.f);
        mh = fmaxf(mh, 1e-12f);
        out[0] = (tot_c > 0.f) ? -logf(mh / (float)BATCH) : 0.f;
    }
}

extern "C" void kernel_launch(void* const* d_in, const int* in_sizes, int n_in,
                              void* d_out, int out_size, void* d_ws, size_t ws_size,
                              hipStream_t stream) {
    const float* feat = (const float*)d_in[0];
    const int* lab = (const int*)d_in[1];
    const int* idx = (const int*)d_in[2];
    float* out = (float*)d_out;
    char* ws = (char*)d_ws;

    int* mbuf            = (int*)(ws + OFF_M);
    float* pairsum       = (float*)(ws + OFF_PAIR);
    unsigned int* counts = (unsigned int*)(ws + OFF_CNT);
    float* sums          = (float*)(ws + OFF_SUM);
    float* partials      = (float*)(ws + OFF_PART);
    unsigned short* keys = (unsigned short*)(ws + OFF_KEYS);

    hipMemsetAsync(ws, 0, ZERO_BYTES, stream);
    k_max<<<dim3(32, BATCH), 256, 0, stream>>>(idx, mbuf);
    k_keys<<<dim3(64, BATCH), 256, 0, stream>>>(lab, idx, mbuf, keys, counts);
    k_sums<<<dim3(XCH, NGRP, BATCH), 256, 0, stream>>>(feat, keys, partials);
    {
        const int tot = BATCH * NGRP * GCH * NSEG;
        k_reduce<<<(tot + 255) / 256, 256, 0, stream>>>(partials, sums);
    }
    k_pairs<<<dim3((NSEG + TI - 1) / TI, (NSEG + TI - 1) / TI, BATCH), 256, 0, stream>>>(
        sums, counts, mbuf, pairsum);
    k_final<<<1, 256, 0, stream>>>(counts, pairsum, mbuf, out);
}